// Round 1
// baseline (294.506 us; speedup 1.0000x reference)
//
#include <hip/hip_runtime.h>
#include <math.h>

#define F_EPS 1e-15f
#define F_BALL_EPS 1e-5f
#define F_TANH_ARG_MAX 15.0f
#define F_ATANH_MAX (1.0f - 1e-7f)

struct Gram { float X2, Y2, XY; };

__device__ __forceinline__ float wave_sum(float v) {
#pragma unroll
    for (int o = 32; o > 0; o >>= 1) v += __shfl_xor(v, o, 64);
    return v;
}

__device__ __forceinline__ float g_norm2(const Gram& g, float a, float b) {
    return fmaxf(a * a * g.X2 + 2.0f * a * b * g.XY + b * b * g.Y2, 0.0f);
}
__device__ __forceinline__ float g_norm(const Gram& g, float a, float b) {
    return fmaxf(sqrtf(g_norm2(g, a, b)), F_EPS);
}
__device__ __forceinline__ float g_dot(const Gram& g, float au, float bu, float av, float bv) {
    return au * av * g.X2 + (au * bv + bu * av) * g.XY + bu * bv * g.Y2;
}

// post_clip in coefficient space
__device__ __forceinline__ void g_postclip(const Gram& g, float maxn, float& a, float& b) {
    float n = g_norm(g, a, b);
    float s = fminf(1.0f, maxn / n);
    a *= s; b *= s;
}

// mobius_scalar_mul(r, u) in coefficient space
__device__ __forceinline__ void g_msm(const Gram& g, float sc, float r, float& a, float& b) {
    float n = g_norm(g, a, b);
    float z = fminf(sc * n, F_ATANH_MAX);
    float f = tanhf(r * atanhf(z)) / (sc * n);
    a *= f; b *= f;
}

// mobius_add(u, v) in coefficient space
__device__ __forceinline__ void g_madd(const Gram& g, float c,
                                       float au, float bu, float av, float bv,
                                       float& ao, float& bo) {
    float u2 = g_norm2(g, au, bu);
    float v2 = g_norm2(g, av, bv);
    float uv = g_dot(g, au, bu, av, bv);
    float A = 1.0f + 2.0f * c * uv + c * v2;
    float B = 1.0f - c * u2;
    float den = fmaxf(1.0f + 2.0f * c * uv + c * c * u2 * v2, F_EPS);
    ao = (A * au + B * av) / den;
    bo = (A * bu + B * bv) / den;
}

// hr = post_clip(expmap0(pre_clip(v, c), c), c) for a pure single-vector row
// with raw norm n; returns the scalar coefficient on v.
__device__ __forceinline__ float hr_coeff(float n, float sc, float maxn_pre, float maxn_post) {
    float s1 = fminf(1.0f, maxn_pre / n);          // pre_clip
    float n1 = fmaxf(s1 * n, F_EPS);
    float f1 = tanhf(sc * n1) / (sc * n1);         // expmap0
    float a  = s1 * f1;
    float n2 = fmaxf(fabsf(a) * n, F_EPS);
    float s2 = fminf(1.0f, maxn_post / n2);        // post_clip
    return a * s2;
}

__global__ __launch_bounds__(256) void hra_kernel(
    const float* __restrict__ x, const float* __restrict__ y,
    const float* __restrict__ p_curv, const float* __restrict__ p_graw,
    const float* __restrict__ p_gscale, const float* __restrict__ p_scent,
    float* __restrict__ out, int rows)
{
    const int wave = (blockIdx.x << 2) | (threadIdx.x >> 6);
    const int lane = threadIdx.x & 63;
    if (wave >= rows) return;

    const float4* xr = (const float4*)(x + (size_t)wave * 768);
    const float4* yr = (const float4*)(y + (size_t)wave * 768);
    float4* outr = (float4*)(out + (size_t)wave * 768);

    float4 xv[3], yv[3];
#pragma unroll
    for (int j = 0; j < 3; j++) {
        xv[j] = xr[lane + 64 * j];
        yv[j] = yr[lane + 64 * j];
    }

    float sxx = 0.0f, syy = 0.0f, sxy = 0.0f;
#pragma unroll
    for (int j = 0; j < 3; j++) {
        sxx += xv[j].x * xv[j].x + xv[j].y * xv[j].y + xv[j].z * xv[j].z + xv[j].w * xv[j].w;
        syy += yv[j].x * yv[j].x + yv[j].y * yv[j].y + yv[j].z * yv[j].z + yv[j].w * yv[j].w;
        sxy += xv[j].x * yv[j].x + xv[j].y * yv[j].y + xv[j].z * yv[j].z + xv[j].w * yv[j].w;
    }
    Gram g;
    g.X2 = wave_sum(sxx);
    g.Y2 = wave_sum(syy);
    g.XY = wave_sum(sxy);

    // --- scalar parameters (uniform) ---
    const float curv = p_curv[0];
    const float graw = p_graw[0];
    const float gscale = p_gscale[0];
    const float scent = p_scent[0];

    const float c  = log1pf(expf(curv));                // softplus
    const float sc = sqrtf(c);
    const float maxn_pre  = F_TANH_ARG_MAX / sc;
    const float maxn_post = (1.0f - F_BALL_EPS) / sc;

    const float s     = 1.0f / (1.0f + expf(-scent));    // sigmoid
    const float g_max = 1.0f + log1pf(expf(gscale));     // 1 + softplus
    const float gamma = g_max * tanhf(graw);

    // --- per-row scalar chain in (a,b) coefficient space: v = a*x + b*y ---
    const float nx = fmaxf(sqrtf(g.X2), F_EPS);
    const float ny = fmaxf(sqrtf(g.Y2), F_EPS);

    const float hx = hr_coeff(nx, sc, maxn_pre, maxn_post);  // hr_x = hx * x
    const float hy = hr_coeff(ny, sc, maxn_pre, maxn_post);  // hr_y = hy * y

    // sx = post_clip(mobius_scalar_mul(s, hr_x))
    float sxa = hx, sxb = 0.0f;
    g_msm(g, sc, s, sxa, sxb);
    g_postclip(g, maxn_post, sxa, sxb);

    // sy = post_clip(mobius_scalar_mul(1-s, hr_y))
    float sya = 0.0f, syb = hy;
    g_msm(g, sc, 1.0f - s, sya, syb);
    g_postclip(g, maxn_post, sya, syb);

    // p = post_clip(mobius_add(sx, sy))
    float pa, pb;
    g_madd(g, c, sxa, sxb, sya, syb, pa, pb);
    g_postclip(g, maxn_post, pa, pb);

    // x_p = post_clip(mobius_add(-p, hr_x))
    float xpa, xpb;
    g_madd(g, c, -pa, -pb, hx, 0.0f, xpa, xpb);
    g_postclip(g, maxn_post, xpa, xpb);

    // y_p = post_clip(mobius_add(-p, hr_y))
    float ypa, ypb;
    g_madd(g, c, -pa, -pb, 0.0f, hy, ypa, ypb);
    g_postclip(g, maxn_post, ypa, ypb);

    // y_s = post_clip(mobius_scalar_mul(gamma, y_p))
    g_msm(g, sc, gamma, ypa, ypb);
    g_postclip(g, maxn_post, ypa, ypb);

    // hres_p = post_clip(mobius_add(x_p, y_s))
    float ha, hb;
    g_madd(g, c, xpa, xpb, ypa, ypb, ha, hb);
    g_postclip(g, maxn_post, ha, hb);

    // hres = mobius_add(p, hres_p); r = post_clip(hres)
    float ra, rb;
    g_madd(g, c, pa, pb, ha, hb, ra, rb);
    g_postclip(g, maxn_post, ra, rb);

    // logmap0
    float nr = g_norm(g, ra, rb);
    float z  = fminf(sc * nr, F_ATANH_MAX);
    float f  = atanhf(z) / (sc * nr);

    const float fa = f * ra;
    const float fb = f * rb;

#pragma unroll
    for (int j = 0; j < 3; j++) {
        float4 o;
        o.x = fa * xv[j].x + fb * yv[j].x;
        o.y = fa * xv[j].y + fb * yv[j].y;
        o.z = fa * xv[j].z + fb * yv[j].z;
        o.w = fa * xv[j].w + fb * yv[j].w;
        outr[lane + 64 * j] = o;
    }
}

extern "C" void kernel_launch(void* const* d_in, const int* in_sizes, int n_in,
                              void* d_out, int out_size, void* d_ws, size_t ws_size,
                              hipStream_t stream) {
    const float* x = (const float*)d_in[0];
    const float* y = (const float*)d_in[1];
    const float* curv = (const float*)d_in[2];
    const float* graw = (const float*)d_in[3];
    const float* gscale = (const float*)d_in[4];
    const float* scent = (const float*)d_in[5];
    float* out = (float*)d_out;

    const int rows = in_sizes[0] / 768;         // (64*577) = 36928
    const int blocks = (rows + 3) / 4;          // 4 waves (rows) per 256-thread block

    hipLaunchKernelGGL(hra_kernel, dim3(blocks), dim3(256), 0, stream,
                       x, y, curv, graw, gscale, scent, out, rows);
}

// Round 2
// 277.757 us; speedup vs baseline: 1.0603x; 1.0603x over previous
//
#include <hip/hip_runtime.h>
#include <math.h>

#define F_EPS 1e-15f
#define F_BALL_EPS 1e-5f
#define F_TANH_ARG_MAX 15.0f
#define F_ATANH_MAX (1.0f - 1e-7f)
#define F_LOG2E 1.4426950408889634f
#define F_LN2   0.6931471805599453f

// ---- fast hardware math (v_rcp/v_sqrt/v_exp/v_log are single instrs) ----
__device__ __forceinline__ float rcp_fast(float x) {
    float r = __builtin_amdgcn_rcpf(x);
    return r * (2.0f - x * r);                  // 1 Newton step -> ~fp32 accurate
}
__device__ __forceinline__ float div_fast(float a, float b) { return a * rcp_fast(b); }
__device__ __forceinline__ float sqrt_fast(float x) { return __builtin_amdgcn_sqrtf(x); }
__device__ __forceinline__ float exp2_fast(float x) { return __builtin_amdgcn_exp2f(x); }
__device__ __forceinline__ float log2_fast(float x) { return __builtin_amdgcn_logf(x); }
__device__ __forceinline__ float exp_fast(float x)  { return exp2_fast(x * F_LOG2E); }

__device__ __forceinline__ float tanh_fast(float x) {
    float ax = fabsf(x);
    float t  = exp2_fast(ax * (-2.0f * F_LOG2E));     // e^{-2|x|}
    float r  = (1.0f - t) * rcp_fast(1.0f + t);
    return copysignf(r, x);
}
__device__ __forceinline__ float atanh_fast(float z) {   // z in [0, 1)
    return (0.5f * F_LN2) * log2_fast((1.0f + z) * rcp_fast(1.0f - z));
}
__device__ __forceinline__ float softplus_fast(float x) {
    return F_LN2 * log2_fast(1.0f + exp2_fast(x * F_LOG2E));
}

struct Gram { float X2, Y2, XY; };

__device__ __forceinline__ float wave_sum(float v) {
#pragma unroll
    for (int o = 32; o > 0; o >>= 1) v += __shfl_xor(v, o, 64);
    return v;
}

__device__ __forceinline__ float g_norm2(const Gram& g, float a, float b) {
    return fmaxf(a * a * g.X2 + 2.0f * a * b * g.XY + b * b * g.Y2, 0.0f);
}
__device__ __forceinline__ float g_norm(const Gram& g, float a, float b) {
    return fmaxf(sqrt_fast(g_norm2(g, a, b)), F_EPS);
}
__device__ __forceinline__ float g_dot(const Gram& g, float au, float bu, float av, float bv) {
    return au * av * g.X2 + (au * bv + bu * av) * g.XY + bu * bv * g.Y2;
}

// post_clip in coefficient space
__device__ __forceinline__ void g_postclip(const Gram& g, float maxn, float& a, float& b) {
    float n = g_norm(g, a, b);
    float s = fminf(1.0f, div_fast(maxn, n));
    a *= s; b *= s;
}

// mobius_scalar_mul(r, u) in coefficient space
__device__ __forceinline__ void g_msm(const Gram& g, float sc, float r, float& a, float& b) {
    float n = g_norm(g, a, b);
    float z = fminf(sc * n, F_ATANH_MAX);
    float f = tanh_fast(r * atanh_fast(z)) * rcp_fast(sc * n);
    a *= f; b *= f;
}

// mobius_add(u, v) in coefficient space
__device__ __forceinline__ void g_madd(const Gram& g, float c,
                                       float au, float bu, float av, float bv,
                                       float& ao, float& bo) {
    float u2 = g_norm2(g, au, bu);
    float v2 = g_norm2(g, av, bv);
    float uv = g_dot(g, au, bu, av, bv);
    float A = 1.0f + 2.0f * c * uv + c * v2;
    float B = 1.0f - c * u2;
    float rden = rcp_fast(fmaxf(1.0f + 2.0f * c * uv + c * c * u2 * v2, F_EPS));
    ao = (A * au + B * av) * rden;
    bo = (A * bu + B * bv) * rden;
}

// hr = post_clip(expmap0(pre_clip(v, c), c), c) for a pure single-vector row.
__device__ __forceinline__ float hr_coeff(float n, float sc, float maxn_pre, float maxn_post) {
    float s1 = fminf(1.0f, div_fast(maxn_pre, n));   // pre_clip
    float n1 = fmaxf(s1 * n, F_EPS);
    float f1 = tanh_fast(sc * n1) * rcp_fast(sc * n1); // expmap0
    float a  = s1 * f1;
    float n2 = fmaxf(fabsf(a) * n, F_EPS);
    float s2 = fminf(1.0f, div_fast(maxn_post, n2)); // post_clip
    return a * s2;
}

__global__ __launch_bounds__(256) void hra_kernel(
    const float* __restrict__ x, const float* __restrict__ y,
    const float* __restrict__ p_curv, const float* __restrict__ p_graw,
    const float* __restrict__ p_gscale, const float* __restrict__ p_scent,
    float* __restrict__ out, int rows)
{
    const int wave = (blockIdx.x << 2) | (threadIdx.x >> 6);
    const int lane = threadIdx.x & 63;
    if (wave >= rows) return;

    const float4* xr = (const float4*)(x + (size_t)wave * 768);
    const float4* yr = (const float4*)(y + (size_t)wave * 768);
    float4* outr = (float4*)(out + (size_t)wave * 768);

    float4 xv[3], yv[3];
#pragma unroll
    for (int j = 0; j < 3; j++) {
        xv[j] = xr[lane + 64 * j];
        yv[j] = yr[lane + 64 * j];
    }

    float sxx = 0.0f, syy = 0.0f, sxy = 0.0f;
#pragma unroll
    for (int j = 0; j < 3; j++) {
        sxx += xv[j].x * xv[j].x + xv[j].y * xv[j].y + xv[j].z * xv[j].z + xv[j].w * xv[j].w;
        syy += yv[j].x * yv[j].x + yv[j].y * yv[j].y + yv[j].z * yv[j].z + yv[j].w * yv[j].w;
        sxy += xv[j].x * yv[j].x + xv[j].y * yv[j].y + xv[j].z * yv[j].z + xv[j].w * yv[j].w;
    }
    Gram g;
    g.X2 = wave_sum(sxx);
    g.Y2 = wave_sum(syy);
    g.XY = wave_sum(sxy);

    // --- scalar parameters (wave-uniform) ---
    const float curv   = p_curv[0];
    const float graw   = p_graw[0];
    const float gscale = p_gscale[0];
    const float scent  = p_scent[0];

    const float c  = softplus_fast(curv);
    const float sc = sqrt_fast(c);
    const float maxn_pre  = div_fast(F_TANH_ARG_MAX, sc);
    const float maxn_post = div_fast(1.0f - F_BALL_EPS, sc);

    const float s     = rcp_fast(1.0f + exp_fast(-scent));  // sigmoid
    const float g_max = 1.0f + softplus_fast(gscale);
    const float gamma = g_max * tanh_fast(graw);

    // --- per-row scalar chain in (a,b) coefficient space: v = a*x + b*y ---
    const float nx = fmaxf(sqrt_fast(g.X2), F_EPS);
    const float ny = fmaxf(sqrt_fast(g.Y2), F_EPS);

    const float hx = hr_coeff(nx, sc, maxn_pre, maxn_post);  // hr_x = hx * x
    const float hy = hr_coeff(ny, sc, maxn_pre, maxn_post);  // hr_y = hy * y

    // sx = post_clip(mobius_scalar_mul(s, hr_x))
    float sxa = hx, sxb = 0.0f;
    g_msm(g, sc, s, sxa, sxb);
    g_postclip(g, maxn_post, sxa, sxb);

    // sy = post_clip(mobius_scalar_mul(1-s, hr_y))
    float sya = 0.0f, syb = hy;
    g_msm(g, sc, 1.0f - s, sya, syb);
    g_postclip(g, maxn_post, sya, syb);

    // p = post_clip(mobius_add(sx, sy))
    float pa, pb;
    g_madd(g, c, sxa, sxb, sya, syb, pa, pb);
    g_postclip(g, maxn_post, pa, pb);

    // x_p = post_clip(mobius_add(-p, hr_x))
    float xpa, xpb;
    g_madd(g, c, -pa, -pb, hx, 0.0f, xpa, xpb);
    g_postclip(g, maxn_post, xpa, xpb);

    // y_p = post_clip(mobius_add(-p, hr_y))
    float ypa, ypb;
    g_madd(g, c, -pa, -pb, 0.0f, hy, ypa, ypb);
    g_postclip(g, maxn_post, ypa, ypb);

    // y_s = post_clip(mobius_scalar_mul(gamma, y_p))
    g_msm(g, sc, gamma, ypa, ypb);
    g_postclip(g, maxn_post, ypa, ypb);

    // hres_p = post_clip(mobius_add(x_p, y_s))
    float ha, hb;
    g_madd(g, c, xpa, xpb, ypa, ypb, ha, hb);
    g_postclip(g, maxn_post, ha, hb);

    // hres = mobius_add(p, hres_p); r = post_clip(hres)
    float ra, rb;
    g_madd(g, c, pa, pb, ha, hb, ra, rb);
    g_postclip(g, maxn_post, ra, rb);

    // logmap0
    float nr = g_norm(g, ra, rb);
    float z  = fminf(sc * nr, F_ATANH_MAX);
    float f  = atanh_fast(z) * rcp_fast(sc * nr);

    const float fa = f * ra;
    const float fb = f * rb;

#pragma unroll
    for (int j = 0; j < 3; j++) {
        float4 o;
        o.x = fa * xv[j].x + fb * yv[j].x;
        o.y = fa * xv[j].y + fb * yv[j].y;
        o.z = fa * xv[j].z + fb * yv[j].z;
        o.w = fa * xv[j].w + fb * yv[j].w;
        outr[lane + 64 * j] = o;
    }
}

extern "C" void kernel_launch(void* const* d_in, const int* in_sizes, int n_in,
                              void* d_out, int out_size, void* d_ws, size_t ws_size,
                              hipStream_t stream) {
    const float* x = (const float*)d_in[0];
    const float* y = (const float*)d_in[1];
    const float* curv = (const float*)d_in[2];
    const float* graw = (const float*)d_in[3];
    const float* gscale = (const float*)d_in[4];
    const float* scent = (const float*)d_in[5];
    float* out = (float*)d_out;

    const int rows = in_sizes[0] / 768;         // 64*577 = 36928
    const int blocks = (rows + 3) / 4;          // 4 waves (rows) per 256-thread block

    hipLaunchKernelGGL(hra_kernel, dim3(blocks), dim3(256), 0, stream,
                       x, y, curv, graw, gscale, scent, out, rows);
}